// Round 3
// baseline (3439.108 us; speedup 1.0000x reference)
//
#include <hip/hip_runtime.h>
#include <hip/hip_bf16.h>
#include <math.h>

// Problem constants
#define B_ 4
#define S_ 2048
#define D_ 1024
#define H_ 16
#define DH_ 64
#define INNER_ 1024   // H_*DH_
#define N3_ 3072      // 3*INNER_
#define ROWS_ 8192    // B_*S_

// ---------------------------------------------------------------------------
// LayerNorm: one block (256 threads) per row of 1024 floats.
// ---------------------------------------------------------------------------
__global__ __launch_bounds__(256) void ln_kernel(const float* __restrict__ x,
                                                 const float* __restrict__ gamma,
                                                 const float* __restrict__ beta,
                                                 float* __restrict__ xn) {
    const int row = blockIdx.x;
    const int tid = threadIdx.x;
    const float4 v = ((const float4*)(x + (size_t)row * D_))[tid];
    float s  = v.x + v.y + v.z + v.w;
    float ss = v.x * v.x + v.y * v.y + v.z * v.z + v.w * v.w;
    #pragma unroll
    for (int off = 32; off > 0; off >>= 1) {
        s  += __shfl_down(s, off);
        ss += __shfl_down(ss, off);
    }
    __shared__ float red[8];
    const int wave = tid >> 6, lane = tid & 63;
    if (lane == 0) { red[wave] = s; red[4 + wave] = ss; }
    __syncthreads();
    const float S  = red[0] + red[1] + red[2] + red[3];
    const float SS = red[4] + red[5] + red[6] + red[7];
    const float mu  = S * (1.0f / D_);
    const float var = SS * (1.0f / D_) - mu * mu;
    const float rs  = rsqrtf(var + 1e-5f);
    const float4 g  = ((const float4*)gamma)[tid];
    const float4 bb = ((const float4*)beta)[tid];
    float4 o;
    o.x = (v.x - mu) * rs * g.x + bb.x;
    o.y = (v.y - mu) * rs * g.y + bb.y;
    o.z = (v.z - mu) * rs * g.z + bb.z;
    o.w = (v.w - mu) * rs * g.w + bb.w;
    ((float4*)(xn + (size_t)row * D_))[tid] = o;
}

// ---------------------------------------------------------------------------
// fp32 SGEMM: C[M,N] = A[M,K] @ B[K,N] (+ bias[N]).  BM=BN=128, BK=16,
// 256 threads, 8x8 micro-tile per thread.
// ---------------------------------------------------------------------------
__global__ __launch_bounds__(256) void sgemm_kernel(const float* __restrict__ A,
                                                    const float* __restrict__ B,
                                                    float* __restrict__ C,
                                                    int M, int N, int K,
                                                    const float* __restrict__ bias) {
    __shared__ float As[16][132];
    __shared__ float Bs[16][132];
    const int tid = threadIdx.x;
    const int tx = tid & 15;
    const int ty = tid >> 4;
    const int m0 = blockIdx.y * 128;
    const int n0 = blockIdx.x * 128;

    float acc[8][8];
    #pragma unroll
    for (int i = 0; i < 8; ++i)
        #pragma unroll
        for (int j = 0; j < 8; ++j) acc[i][j] = 0.0f;

    const int a_row = tid >> 2;         // 0..63
    const int a_k   = (tid & 3) * 4;    // 0,4,8,12

    for (int k0 = 0; k0 < K; k0 += 16) {
        #pragma unroll
        for (int l = 0; l < 2; ++l) {
            const int r = a_row + l * 64;
            const float4 v = *(const float4*)(A + (size_t)(m0 + r) * K + k0 + a_k);
            As[a_k + 0][r] = v.x;
            As[a_k + 1][r] = v.y;
            As[a_k + 2][r] = v.z;
            As[a_k + 3][r] = v.w;
        }
        #pragma unroll
        for (int l = 0; l < 2; ++l) {
            const int f  = tid + l * 256;
            const int kk = f >> 5;
            const int nn = (f & 31) * 4;
            *(float4*)(&Bs[kk][nn]) = *(const float4*)(B + (size_t)(k0 + kk) * N + n0 + nn);
        }
        __syncthreads();
        #pragma unroll
        for (int kk = 0; kk < 16; ++kk) {
            float a[8], b[8];
            *(float4*)(a)     = *(const float4*)(&As[kk][ty * 4]);
            *(float4*)(a + 4) = *(const float4*)(&As[kk][64 + ty * 4]);
            *(float4*)(b)     = *(const float4*)(&Bs[kk][tx * 4]);
            *(float4*)(b + 4) = *(const float4*)(&Bs[kk][64 + tx * 4]);
            #pragma unroll
            for (int i = 0; i < 8; ++i)
                #pragma unroll
                for (int j = 0; j < 8; ++j) acc[i][j] += a[i] * b[j];
        }
        __syncthreads();
    }

    #pragma unroll
    for (int ih = 0; ih < 2; ++ih) {
        #pragma unroll
        for (int i = 0; i < 4; ++i) {
            const int r = m0 + ih * 64 + ty * 4 + i;
            float* crow = C + (size_t)r * N + n0;
            #pragma unroll
            for (int jh = 0; jh < 2; ++jh) {
                const int c0 = jh * 64 + tx * 4;
                float4 v;
                v.x = acc[ih * 4 + i][jh * 4 + 0];
                v.y = acc[ih * 4 + i][jh * 4 + 1];
                v.z = acc[ih * 4 + i][jh * 4 + 2];
                v.w = acc[ih * 4 + i][jh * 4 + 3];
                if (bias) {
                    const float4 bv = *(const float4*)(bias + n0 + c0);
                    v.x += bv.x; v.y += bv.y; v.z += bv.z; v.w += bv.w;
                }
                *(float4*)(crow + c0) = v;
            }
        }
    }
}

// ---------------------------------------------------------------------------
// RoPE cos/sin table: [S_][32] each.
// ---------------------------------------------------------------------------
__global__ __launch_bounds__(256) void rope_table_kernel(float* __restrict__ cost,
                                                         float* __restrict__ sint) {
    const int idx = blockIdx.x * 256 + threadIdx.x;  // 0..65535
    const int s = idx >> 5;
    const int i = idx & 31;
    const float inv = powf(10000.0f, -(2.0f * (float)i) / 64.0f);
    const float f = (float)s * inv;
    float sv, cv;
    sincosf(f, &sv, &cv);
    cost[idx] = cv;
    sint[idx] = sv;
}

// ---------------------------------------------------------------------------
// RoPE apply, in-place on q and k halves of the qkv buffer.
// ---------------------------------------------------------------------------
__global__ __launch_bounds__(256) void rope_apply_kernel(float* __restrict__ qkv,
                                                         const float* __restrict__ cost,
                                                         const float* __restrict__ sint) {
    const int idx = blockIdx.x * 256 + threadIdx.x;  // B_*S_*H_*32
    const int d = idx & 31;
    const int h = (idx >> 5) & 15;
    const int row = idx >> 9;        // b*S_+s, 0..8191
    const int spos = row & (S_ - 1);
    const size_t base = (size_t)row * N3_ + h * 64 + d;
    const float c  = cost[spos * 32 + d];
    const float sn = sint[spos * 32 + d];
    const float q1 = qkv[base], q2 = qkv[base + 32];
    qkv[base]      = q1 * c - q2 * sn;
    qkv[base + 32] = q1 * sn + q2 * c;
    const float k1 = qkv[base + 1024], k2 = qkv[base + 1056];
    qkv[base + 1024] = k1 * c - k2 * sn;
    qkv[base + 1056] = k1 * sn + k2 * c;
}

// ---------------------------------------------------------------------------
// Flash attention v3 (fp32), register-blocked, spill-free.
// Block = 256 threads handles 256 q-rows of one (b,h).
// 4-lane group = 4 q-rows x full 64 dims; lane&3 picks a 16-dim slice.
// Each thread: q[4][16], o[4][16], online softmax m[4], l[4].
// Scores processed in 8-j chunks (sc[4][8] = 32 regs) to keep peak live
// registers ~190 < 256 (round-2 regression: __launch_bounds__(256,2) capped
// VGPR at 128 -> 2.3 GB of scratch spills; plain (256) gives ~236 VGPR).
// ---------------------------------------------------------------------------
__global__ __launch_bounds__(256) void attn_kernel(const float* __restrict__ qkv,
                                                   float* __restrict__ att) {
    __shared__ float Kt[64][64];
    __shared__ float Vt[64][64];
    const int tid  = threadIdx.x;
    const int lane = tid & 63;
    const int wave = tid >> 6;
    const int ds   = lane & 3;        // d-slice 0..3 (dims ds*16..ds*16+15)
    const int rg   = lane >> 2;       // row group 0..15
    const int bh = blockIdx.x;
    const int b = bh >> 4;
    const int h = bh & 15;
    const int row0 = blockIdx.y * 256 + wave * 64 + rg * 4;  // 4 rows

    // Load q fragments (scaled by 1/sqrt(64))
    float q[4][16];
    #pragma unroll
    for (int r = 0; r < 4; ++r) {
        const size_t qb = ((size_t)(b * S_ + row0 + r)) * N3_ + h * 64 + ds * 16;
        #pragma unroll
        for (int i = 0; i < 4; ++i) {
            const float4 v = *(const float4*)(qkv + qb + i * 4);
            q[r][i * 4 + 0] = v.x * 0.125f;
            q[r][i * 4 + 1] = v.y * 0.125f;
            q[r][i * 4 + 2] = v.z * 0.125f;
            q[r][i * 4 + 3] = v.w * 0.125f;
        }
    }
    float o[4][16];
    #pragma unroll
    for (int r = 0; r < 4; ++r)
        #pragma unroll
        for (int d = 0; d < 16; ++d) o[r][d] = 0.0f;
    float m[4] = {-1e30f, -1e30f, -1e30f, -1e30f};
    float l[4] = {0.0f, 0.0f, 0.0f, 0.0f};

    const size_t kvbase = ((size_t)b * S_) * N3_ + h * 64;

    for (int j0 = 0; j0 < S_; j0 += 64) {
        __syncthreads();
        #pragma unroll
        for (int ld = 0; ld < 4; ++ld) {
            const int f = tid + ld * 256;      // 0..1023
            const int jj = f >> 4;
            const int dseg = (f & 15) * 4;
            const size_t g = kvbase + (size_t)(j0 + jj) * N3_ + dseg;
            *(float4*)(&Kt[jj][dseg]) = *(const float4*)(qkv + g + 1024);
            *(float4*)(&Vt[jj][dseg]) = *(const float4*)(qkv + g + 2048);
        }
        __syncthreads();

        #pragma unroll
        for (int chunk = 0; chunk < 8; ++chunk) {
            float sc[4][8];
            // ---- QK^T for 8 j's ----
            #pragma unroll
            for (int jj = 0; jj < 8; ++jj) {
                const int j = chunk * 8 + jj;
                float kv[16];
                #pragma unroll
                for (int i = 0; i < 4; ++i)
                    *(float4*)(&kv[i * 4]) = *(const float4*)(&Kt[j][ds * 16 + i * 4]);
                #pragma unroll
                for (int r = 0; r < 4; ++r) {
                    float p0 = 0, p1 = 0, p2 = 0, p3 = 0;
                    #pragma unroll
                    for (int i = 0; i < 4; ++i) {
                        p0 += q[r][i * 4 + 0] * kv[i * 4 + 0];
                        p1 += q[r][i * 4 + 1] * kv[i * 4 + 1];
                        p2 += q[r][i * 4 + 2] * kv[i * 4 + 2];
                        p3 += q[r][i * 4 + 3] * kv[i * 4 + 3];
                    }
                    sc[r][jj] = (p0 + p1) + (p2 + p3);
                }
            }
            // ---- reduce partial dots across the 4 slice-lanes ----
            #pragma unroll
            for (int r = 0; r < 4; ++r)
                #pragma unroll
                for (int jj = 0; jj < 8; ++jj) {
                    float v = sc[r][jj];
                    v += __shfl_xor(v, 1);
                    v += __shfl_xor(v, 2);
                    sc[r][jj] = v;
                }
            // ---- online softmax update (per row) ----
            #pragma unroll
            for (int r = 0; r < 4; ++r) {
                float cm = sc[r][0];
                #pragma unroll
                for (int jj = 1; jj < 8; ++jj) cm = fmaxf(cm, sc[r][jj]);
                const float mn = fmaxf(m[r], cm);
                const float fac = __expf(m[r] - mn);
                m[r] = mn;
                float ps = 0.0f;
                #pragma unroll
                for (int jj = 0; jj < 8; ++jj) {
                    sc[r][jj] = __expf(sc[r][jj] - mn);
                    ps += sc[r][jj];
                }
                l[r] = l[r] * fac + ps;
                #pragma unroll
                for (int d = 0; d < 16; ++d) o[r][d] *= fac;
            }
            // ---- PV accumulate ----
            #pragma unroll
            for (int jj = 0; jj < 8; ++jj) {
                const int j = chunk * 8 + jj;
                float vv[16];
                #pragma unroll
                for (int i = 0; i < 4; ++i)
                    *(float4*)(&vv[i * 4]) = *(const float4*)(&Vt[j][ds * 16 + i * 4]);
                #pragma unroll
                for (int r = 0; r < 4; ++r) {
                    const float pj = sc[r][jj];
                    #pragma unroll
                    for (int d = 0; d < 16; ++d) o[r][d] += pj * vv[d];
                }
            }
        }
    }

    // ---- write out ----
    #pragma unroll
    for (int r = 0; r < 4; ++r) {
        const float inv_l = 1.0f / l[r];
        const size_t ob = ((size_t)(b * S_ + row0 + r)) * INNER_ + h * 64 + ds * 16;
        #pragma unroll
        for (int i = 0; i < 4; ++i) {
            float4 ov;
            ov.x = o[r][i * 4 + 0] * inv_l;
            ov.y = o[r][i * 4 + 1] * inv_l;
            ov.z = o[r][i * 4 + 2] * inv_l;
            ov.w = o[r][i * 4 + 3] * inv_l;
            *(float4*)(att + ob + i * 4) = ov;
        }
    }
}

// ---------------------------------------------------------------------------
// Launch
// ---------------------------------------------------------------------------
extern "C" void kernel_launch(void* const* d_in, const int* in_sizes, int n_in,
                              void* d_out, int out_size, void* d_ws, size_t ws_size,
                              hipStream_t stream) {
    const float* x        = (const float*)d_in[0];
    const float* w_qkv    = (const float*)d_in[1];
    const float* w_out    = (const float*)d_in[2];
    const float* b_out    = (const float*)d_in[3];
    const float* ln_gamma = (const float*)d_in[4];
    const float* ln_beta  = (const float*)d_in[5];
    float* out = (float*)d_out;

    float* ws = (float*)d_ws;
    float* xn   = ws;                         // 8192*1024 (reused as att)
    float* qkv  = ws + (size_t)ROWS_ * D_;    // 8192*3072
    float* cost = qkv + (size_t)ROWS_ * N3_;  // 65536
    float* sint = cost + S_ * 32;             // 65536
    float* att  = xn;                         // reuse: xn dead after qkv gemm

    // 1. LayerNorm
    ln_kernel<<<ROWS_, 256, 0, stream>>>(x, ln_gamma, ln_beta, xn);

    // 2. QKV projection: [8192,1024] @ [1024,3072]
    sgemm_kernel<<<dim3(N3_ / 128, ROWS_ / 128), 256, 0, stream>>>(
        xn, w_qkv, qkv, ROWS_, N3_, D_, nullptr);

    // 3. RoPE table + apply
    rope_table_kernel<<<(S_ * 32) / 256, 256, 0, stream>>>(cost, sint);
    rope_apply_kernel<<<(B_ * S_ * H_ * 32) / 256, 256, 0, stream>>>(qkv, cost, sint);

    // 4. Attention (v3: register-blocked, spill-free)
    attn_kernel<<<dim3(B_ * H_, S_ / 256), 256, 0, stream>>>(qkv, att);

    // 5. Output projection + bias: [8192,1024] @ [1024,1024] + b_out
    sgemm_kernel<<<dim3(D_ / 128, ROWS_ / 128), 256, 0, stream>>>(
        att, w_out, out, ROWS_, D_, INNER_, b_out);
}

// Round 4
// 1230.132 us; speedup vs baseline: 2.7957x; 2.7957x over previous
//
#include <hip/hip_runtime.h>
#include <hip/hip_bf16.h>
#include <math.h>

// Problem constants
#define B_ 4
#define S_ 2048
#define D_ 1024
#define H_ 16
#define DH_ 64
#define INNER_ 1024   // H_*DH_
#define N3_ 3072      // 3*INNER_
#define ROWS_ 8192    // B_*S_

typedef __attribute__((ext_vector_type(8))) short short8;
typedef __attribute__((ext_vector_type(4))) float f32x4;

// ---------------------------------------------------------------------------
// LayerNorm: one block (256 threads) per row of 1024 floats.
// ---------------------------------------------------------------------------
__global__ __launch_bounds__(256) void ln_kernel(const float* __restrict__ x,
                                                 const float* __restrict__ gamma,
                                                 const float* __restrict__ beta,
                                                 float* __restrict__ xn) {
    const int row = blockIdx.x;
    const int tid = threadIdx.x;
    const float4 v = ((const float4*)(x + (size_t)row * D_))[tid];
    float s  = v.x + v.y + v.z + v.w;
    float ss = v.x * v.x + v.y * v.y + v.z * v.z + v.w * v.w;
    #pragma unroll
    for (int off = 32; off > 0; off >>= 1) {
        s  += __shfl_down(s, off);
        ss += __shfl_down(ss, off);
    }
    __shared__ float red[8];
    const int wave = tid >> 6, lane = tid & 63;
    if (lane == 0) { red[wave] = s; red[4 + wave] = ss; }
    __syncthreads();
    const float S  = red[0] + red[1] + red[2] + red[3];
    const float SS = red[4] + red[5] + red[6] + red[7];
    const float mu  = S * (1.0f / D_);
    const float var = SS * (1.0f / D_) - mu * mu;
    const float rs  = rsqrtf(var + 1e-5f);
    const float4 g  = ((const float4*)gamma)[tid];
    const float4 bb = ((const float4*)beta)[tid];
    float4 o;
    o.x = (v.x - mu) * rs * g.x + bb.x;
    o.y = (v.y - mu) * rs * g.y + bb.y;
    o.z = (v.z - mu) * rs * g.z + bb.z;
    o.w = (v.w - mu) * rs * g.w + bb.w;
    ((float4*)(xn + (size_t)row * D_))[tid] = o;
}

// ---------------------------------------------------------------------------
// fp32 SGEMM: C[M,N] = A[M,K] @ B[K,N] (+ bias[N]).  BM=BN=128, BK=16,
// 256 threads, 8x8 micro-tile per thread.
// ---------------------------------------------------------------------------
__global__ __launch_bounds__(256) void sgemm_kernel(const float* __restrict__ A,
                                                    const float* __restrict__ B,
                                                    float* __restrict__ C,
                                                    int M, int N, int K,
                                                    const float* __restrict__ bias) {
    __shared__ float As[16][132];
    __shared__ float Bs[16][132];
    const int tid = threadIdx.x;
    const int tx = tid & 15;
    const int ty = tid >> 4;
    const int m0 = blockIdx.y * 128;
    const int n0 = blockIdx.x * 128;

    float acc[8][8];
    #pragma unroll
    for (int i = 0; i < 8; ++i)
        #pragma unroll
        for (int j = 0; j < 8; ++j) acc[i][j] = 0.0f;

    const int a_row = tid >> 2;
    const int a_k   = (tid & 3) * 4;

    for (int k0 = 0; k0 < K; k0 += 16) {
        #pragma unroll
        for (int l = 0; l < 2; ++l) {
            const int r = a_row + l * 64;
            const float4 v = *(const float4*)(A + (size_t)(m0 + r) * K + k0 + a_k);
            As[a_k + 0][r] = v.x;
            As[a_k + 1][r] = v.y;
            As[a_k + 2][r] = v.z;
            As[a_k + 3][r] = v.w;
        }
        #pragma unroll
        for (int l = 0; l < 2; ++l) {
            const int f  = tid + l * 256;
            const int kk = f >> 5;
            const int nn = (f & 31) * 4;
            *(float4*)(&Bs[kk][nn]) = *(const float4*)(B + (size_t)(k0 + kk) * N + n0 + nn);
        }
        __syncthreads();
        #pragma unroll
        for (int kk = 0; kk < 16; ++kk) {
            float a[8], b[8];
            *(float4*)(a)     = *(const float4*)(&As[kk][ty * 4]);
            *(float4*)(a + 4) = *(const float4*)(&As[kk][64 + ty * 4]);
            *(float4*)(b)     = *(const float4*)(&Bs[kk][tx * 4]);
            *(float4*)(b + 4) = *(const float4*)(&Bs[kk][64 + tx * 4]);
            #pragma unroll
            for (int i = 0; i < 8; ++i)
                #pragma unroll
                for (int j = 0; j < 8; ++j) acc[i][j] += a[i] * b[j];
        }
        __syncthreads();
    }

    #pragma unroll
    for (int ih = 0; ih < 2; ++ih) {
        #pragma unroll
        for (int i = 0; i < 4; ++i) {
            const int r = m0 + ih * 64 + ty * 4 + i;
            float* crow = C + (size_t)r * N + n0;
            #pragma unroll
            for (int jh = 0; jh < 2; ++jh) {
                const int c0 = jh * 64 + tx * 4;
                float4 v;
                v.x = acc[ih * 4 + i][jh * 4 + 0];
                v.y = acc[ih * 4 + i][jh * 4 + 1];
                v.z = acc[ih * 4 + i][jh * 4 + 2];
                v.w = acc[ih * 4 + i][jh * 4 + 3];
                if (bias) {
                    const float4 bv = *(const float4*)(bias + n0 + c0);
                    v.x += bv.x; v.y += bv.y; v.z += bv.z; v.w += bv.w;
                }
                *(float4*)(crow + c0) = v;
            }
        }
    }
}

// ---------------------------------------------------------------------------
// RoPE cos/sin table: [S_][32] each.
// ---------------------------------------------------------------------------
__global__ __launch_bounds__(256) void rope_table_kernel(float* __restrict__ cost,
                                                         float* __restrict__ sint) {
    const int idx = blockIdx.x * 256 + threadIdx.x;
    const int s = idx >> 5;
    const int i = idx & 31;
    const float inv = powf(10000.0f, -(2.0f * (float)i) / 64.0f);
    const float f = (float)s * inv;
    float sv, cv;
    sincosf(f, &sv, &cv);
    cost[idx] = cv;
    sint[idx] = sv;
}

// ---------------------------------------------------------------------------
// RoPE apply, in-place on q and k halves of the qkv buffer.
// ---------------------------------------------------------------------------
__global__ __launch_bounds__(256) void rope_apply_kernel(float* __restrict__ qkv,
                                                         const float* __restrict__ cost,
                                                         const float* __restrict__ sint) {
    const int idx = blockIdx.x * 256 + threadIdx.x;
    const int d = idx & 31;
    const int h = (idx >> 5) & 15;
    const int row = idx >> 9;
    const int spos = row & (S_ - 1);
    const size_t base = (size_t)row * N3_ + h * 64 + d;
    const float c  = cost[spos * 32 + d];
    const float sn = sint[spos * 32 + d];
    const float q1 = qkv[base], q2 = qkv[base + 32];
    qkv[base]      = q1 * c - q2 * sn;
    qkv[base + 32] = q1 * sn + q2 * c;
    const float k1 = qkv[base + 1024], k2 = qkv[base + 1056];
    qkv[base + 1024] = k1 * c - k2 * sn;
    qkv[base + 1056] = k1 * sn + k2 * c;
}

// ---------------------------------------------------------------------------
// split fp32 -> bf16 hi + bf16 lo (hi+lo reproduces ~16 mantissa bits)
// ---------------------------------------------------------------------------
__device__ __forceinline__ void split2(float x, ushort& hi, ushort& lo) {
    __hip_bfloat16 h = __float2bfloat16(x);
    float hf = __bfloat162float(h);
    __hip_bfloat16 l = __float2bfloat16(x - hf);
    hi = *reinterpret_cast<ushort*>(&h);
    lo = *reinterpret_cast<ushort*>(&l);
}

// XOR-swizzled byte offset into a row-major [.][64] bf16 tile (128B rows).
__device__ __forceinline__ int swz(int row, int colByte) {
    return row * 128 + (colByte ^ ((row & 7) << 4));
}

// ---------------------------------------------------------------------------
// Flash attention v4: split-bf16 MFMA (16x16x32), fp32-grade accuracy.
// Block = 4 waves = 64 q-rows of one (b,h); wave w owns rows w*16..w*16+15.
// Per 64-j KV tile: QK^T = Qh*Kh + Qh*Kl + Ql*Kh (24 mfma), online softmax
// in C-layout regs (row=(lane>>4)*4+reg, col=lane&15, m89-verified), P split
// to per-wave LDS, PV = Ph*Vh + Ph*Vl + Pl*Vh (24 mfma).
// K LDS [j][d], V LDS transposed [d][j], P LDS [q][j]; all XOR-swizzled so
// B/A-fragment ds_read_b128 (16 rows x same 16B column slot) is conflict-free.
// ---------------------------------------------------------------------------
__global__ __launch_bounds__(256) void attn_mfma_kernel(const float* __restrict__ qkv,
                                                        float* __restrict__ att) {
    __shared__ __align__(16) ushort Kh[64 * 64], Kl[64 * 64];
    __shared__ __align__(16) ushort Vh[64 * 64], Vl[64 * 64];
    __shared__ __align__(16) ushort Ph[4][16 * 64], Pl[4][16 * 64];

    const int tid  = threadIdx.x;
    const int lane = tid & 63;
    const int wv   = tid >> 6;
    const int lr   = lane & 15;   // row/col-within-16 index
    const int lg   = lane >> 4;   // k-group 0..3

    const int bh = blockIdx.x;
    const int b  = bh >> 4;
    const int h  = bh & 15;
    const int q0 = blockIdx.y * 64;

    // ---- Q fragments (A operand), held in registers for the whole kernel.
    // A-frag: lane holds A[row=lane&15][k=(lane>>4)*8+i]; 2 k-chunks (d 0-31, 32-63).
    const int qrow = q0 + wv * 16 + lr;
    const float* qp = qkv + ((size_t)(b * S_ + qrow)) * N3_ + h * 64;
    short8 qh[2], ql[2];
    #pragma unroll
    for (int kc = 0; kc < 2; ++kc) {
        float t8[8];
        *(float4*)(t8)     = *(const float4*)(qp + kc * 32 + lg * 8);
        *(float4*)(t8 + 4) = *(const float4*)(qp + kc * 32 + lg * 8 + 4);
        #pragma unroll
        for (int i = 0; i < 8; ++i) {
            ushort hi, lo;
            split2(t8[i] * 0.125f, hi, lo);
            qh[kc][i] = (short)hi;
            ql[kc][i] = (short)lo;
        }
    }

    f32x4 accO[4];
    #pragma unroll
    for (int t = 0; t < 4; ++t) accO[t] = (f32x4){0.f, 0.f, 0.f, 0.f};
    float mrun[4] = {-1e30f, -1e30f, -1e30f, -1e30f};
    float lrun[4] = {0.f, 0.f, 0.f, 0.f};

    // staging indices
    const int kj = tid >> 2;                  // K: row 0..63
    const int kd = (tid & 3) * 16;            // K: d base 0,16,32,48
    const int vjp = tid >> 3;                 // V: j-pair 0..31
    const int vdb = (tid & 7) * 8;            // V: d base 0..56

    for (int j0 = 0; j0 < S_; j0 += 64) {
        __syncthreads();   // previous tile fully consumed

        // ---- stage K tile (64x64) as bf16 hi/lo, layout [j][d], swizzled
        {
            const float* krow = qkv + ((size_t)(b * S_ + j0 + kj)) * N3_ + 1024 + h * 64;
            #pragma unroll
            for (int f = 0; f < 4; ++f) {
                float t4[4];
                *(float4*)t4 = *(const float4*)(krow + kd + f * 4);
                ushort hb[4], lb[4];
                #pragma unroll
                for (int i = 0; i < 4; ++i) split2(t4[i], hb[i], lb[i]);
                const int off = swz(kj, (kd + f * 4) * 2);
                *(ushort4*)((char*)Kh + off) = make_ushort4(hb[0], hb[1], hb[2], hb[3]);
                *(ushort4*)((char*)Kl + off) = make_ushort4(lb[0], lb[1], lb[2], lb[3]);
            }
        }
        // ---- stage V tile transposed: Vt[d][j], bf16 hi/lo, swizzled.
        // thread handles j-pair (2 rows) x 8 dims -> packed b32 writes.
        {
            const float* vrow0 = qkv + ((size_t)(b * S_ + j0 + 2 * vjp)) * N3_ + 2048 + h * 64 + vdb;
            const float* vrow1 = vrow0 + N3_;
            float r0[8], r1[8];
            *(float4*)(r0)     = *(const float4*)(vrow0);
            *(float4*)(r0 + 4) = *(const float4*)(vrow0 + 4);
            *(float4*)(r1)     = *(const float4*)(vrow1);
            *(float4*)(r1 + 4) = *(const float4*)(vrow1 + 4);
            #pragma unroll
            for (int i = 0; i < 8; ++i) {
                const int d = vdb + i;
                ushort h0, l0, h1, l1;
                split2(r0[i], h0, l0);
                split2(r1[i], h1, l1);
                const int off = swz(d, vjp * 4);
                *(uint*)((char*)Vh + off) = (uint)h0 | ((uint)h1 << 16);
                *(uint*)((char*)Vl + off) = (uint)l0 | ((uint)l1 << 16);
            }
        }
        __syncthreads();

        // ---- QK^T: 4 j-tiles x 2 k-chunks x 3 split terms = 24 mfma
        f32x4 accS[4];
        #pragma unroll
        for (int t = 0; t < 4; ++t) accS[t] = (f32x4){0.f, 0.f, 0.f, 0.f};
        #pragma unroll
        for (int kc = 0; kc < 2; ++kc) {
            #pragma unroll
            for (int t = 0; t < 4; ++t) {
                const int off = swz(t * 16 + lr, (kc * 32 + lg * 8) * 2);
                short8 bhf = *(short8*)((char*)Kh + off);
                short8 blf = *(short8*)((char*)Kl + off);
                accS[t] = __builtin_amdgcn_mfma_f32_16x16x32_bf16(qh[kc], bhf, accS[t], 0, 0, 0);
                accS[t] = __builtin_amdgcn_mfma_f32_16x16x32_bf16(qh[kc], blf, accS[t], 0, 0, 0);
                accS[t] = __builtin_amdgcn_mfma_f32_16x16x32_bf16(ql[kc], bhf, accS[t], 0, 0, 0);
            }
        }

        // ---- online softmax on C-layout scores: row=(lg)*4+r, col j=t*16+lr
        float p[4][4];   // [t][r]
        float fac[4];
        #pragma unroll
        for (int r = 0; r < 4; ++r) {
            float v = fmaxf(fmaxf(accS[0][r], accS[1][r]), fmaxf(accS[2][r], accS[3][r]));
            v = fmaxf(v, __shfl_xor(v, 1));
            v = fmaxf(v, __shfl_xor(v, 2));
            v = fmaxf(v, __shfl_xor(v, 4));
            v = fmaxf(v, __shfl_xor(v, 8));
            const float mn = fmaxf(mrun[r], v);
            fac[r] = __expf(mrun[r] - mn);
            mrun[r] = mn;
            float rs = 0.f;
            #pragma unroll
            for (int t = 0; t < 4; ++t) {
                p[t][r] = __expf(accS[t][r] - mn);
                rs += p[t][r];
            }
            rs += __shfl_xor(rs, 1);
            rs += __shfl_xor(rs, 2);
            rs += __shfl_xor(rs, 4);
            rs += __shfl_xor(rs, 8);
            lrun[r] = lrun[r] * fac[r] + rs;
        }
        #pragma unroll
        for (int t = 0; t < 4; ++t)
            #pragma unroll
            for (int r = 0; r < 4; ++r) accO[t][r] *= fac[r];

        // ---- store P (split) to per-wave LDS, layout [q_local][j], swizzled
        #pragma unroll
        for (int t = 0; t < 4; ++t)
            #pragma unroll
            for (int r = 0; r < 4; ++r) {
                ushort hi, lo;
                split2(p[t][r], hi, lo);
                const int off = swz(lg * 4 + r, (t * 16 + lr) * 2);
                *(ushort*)((char*)Ph[wv] + off) = hi;
                *(ushort*)((char*)Pl[wv] + off) = lo;
            }

        // ---- PV: O += P * V.  2 j-chunks x (4 d-tiles x 3 split) = 24 mfma
        #pragma unroll
        for (int jc = 0; jc < 2; ++jc) {
            const int aoff = swz(lr, (jc * 32 + lg * 8) * 2);
            short8 pah = *(short8*)((char*)Ph[wv] + aoff);
            short8 pal = *(short8*)((char*)Pl[wv] + aoff);
            #pragma unroll
            for (int dt = 0; dt < 4; ++dt) {
                const int boff = swz(dt * 16 + lr, (jc * 32 + lg * 8) * 2);
                short8 vhf = *(short8*)((char*)Vh + boff);
                short8 vlf = *(short8*)((char*)Vl + boff);
                accO[dt] = __builtin_amdgcn_mfma_f32_16x16x32_bf16(pah, vhf, accO[dt], 0, 0, 0);
                accO[dt] = __builtin_amdgcn_mfma_f32_16x16x32_bf16(pah, vlf, accO[dt], 0, 0, 0);
                accO[dt] = __builtin_amdgcn_mfma_f32_16x16x32_bf16(pal, vhf, accO[dt], 0, 0, 0);
            }
        }
    }

    // ---- normalize and write out: O row q=(lg)*4+r, col d=dt*16+lr
    #pragma unroll
    for (int r = 0; r < 4; ++r) {
        const float inv_l = 1.0f / lrun[r];
        const int q = q0 + wv * 16 + lg * 4 + r;
        float* orow = att + ((size_t)(b * S_ + q)) * INNER_ + h * 64;
        #pragma unroll
        for (int dt = 0; dt < 4; ++dt) {
            orow[dt * 16 + lr] = accO[dt][r] * inv_l;
        }
    }
}

// ---------------------------------------------------------------------------
// Launch
// ---------------------------------------------------------------------------
extern "C" void kernel_launch(void* const* d_in, const int* in_sizes, int n_in,
                              void* d_out, int out_size, void* d_ws, size_t ws_size,
                              hipStream_t stream) {
    const float* x        = (const float*)d_in[0];
    const float* w_qkv    = (const float*)d_in[1];
    const float* w_out    = (const float*)d_in[2];
    const float* b_out    = (const float*)d_in[3];
    const float* ln_gamma = (const float*)d_in[4];
    const float* ln_beta  = (const float*)d_in[5];
    float* out = (float*)d_out;

    float* ws = (float*)d_ws;
    float* xn   = ws;                         // 8192*1024 (reused as att)
    float* qkv  = ws + (size_t)ROWS_ * D_;    // 8192*3072
    float* cost = qkv + (size_t)ROWS_ * N3_;  // 65536
    float* sint = cost + S_ * 32;             // 65536
    float* att  = xn;                         // reuse: xn dead after qkv gemm

    // 1. LayerNorm
    ln_kernel<<<ROWS_, 256, 0, stream>>>(x, ln_gamma, ln_beta, xn);

    // 2. QKV projection: [8192,1024] @ [1024,3072]
    sgemm_kernel<<<dim3(N3_ / 128, ROWS_ / 128), 256, 0, stream>>>(
        xn, w_qkv, qkv, ROWS_, N3_, D_, nullptr);

    // 3. RoPE table + apply
    rope_table_kernel<<<(S_ * 32) / 256, 256, 0, stream>>>(cost, sint);
    rope_apply_kernel<<<(B_ * S_ * H_ * 32) / 256, 256, 0, stream>>>(qkv, cost, sint);

    // 4. Attention (v4: split-bf16 MFMA flash attention)
    attn_mfma_kernel<<<dim3(B_ * H_, S_ / 64), 256, 0, stream>>>(qkv, att);

    // 5. Output projection + bias: [8192,1024] @ [1024,1024] + b_out
    sgemm_kernel<<<dim3(D_ / 128, ROWS_ / 128), 256, 0, stream>>>(
        att, w_out, out, ROWS_, D_, INNER_, b_out);
}

// Round 5
// 676.777 us; speedup vs baseline: 5.0816x; 1.8176x over previous
//
#include <hip/hip_runtime.h>
#include <hip/hip_bf16.h>
#include <math.h>

// Problem constants
#define B_ 4
#define S_ 2048
#define D_ 1024
#define H_ 16
#define DH_ 64
#define INNER_ 1024   // H_*DH_
#define N3_ 3072      // 3*INNER_
#define ROWS_ 8192    // B_*S_

typedef __attribute__((ext_vector_type(8))) short short8;
typedef __attribute__((ext_vector_type(4))) float f32x4;

// ---------------------------------------------------------------------------
// split fp32 -> bf16 hi + bf16 lo (hi+lo reproduces ~16 mantissa bits)
// ---------------------------------------------------------------------------
__device__ __forceinline__ void split2(float x, ushort& hi, ushort& lo) {
    __hip_bfloat16 h = __float2bfloat16(x);
    float hf = __bfloat162float(h);
    __hip_bfloat16 l = __float2bfloat16(x - hf);
    hi = *reinterpret_cast<ushort*>(&h);
    lo = *reinterpret_cast<ushort*>(&l);
}

// XOR-swizzled byte offset into a row-major [.][64] bf16 tile (128B rows).
__device__ __forceinline__ int swz(int row, int colByte) {
    return row * 128 + (colByte ^ ((row & 7) << 4));
}

// ---------------------------------------------------------------------------
// LayerNorm: one block (256 threads) per row of 1024 floats.
// Emits pre-split bf16 hi/lo for the MFMA QKV GEMM.
// ---------------------------------------------------------------------------
__global__ __launch_bounds__(256) void ln_kernel(const float* __restrict__ x,
                                                 const float* __restrict__ gamma,
                                                 const float* __restrict__ beta,
                                                 ushort* __restrict__ xn_h,
                                                 ushort* __restrict__ xn_l) {
    const int row = blockIdx.x;
    const int tid = threadIdx.x;
    const float4 v = ((const float4*)(x + (size_t)row * D_))[tid];
    float s  = v.x + v.y + v.z + v.w;
    float ss = v.x * v.x + v.y * v.y + v.z * v.z + v.w * v.w;
    #pragma unroll
    for (int off = 32; off > 0; off >>= 1) {
        s  += __shfl_down(s, off);
        ss += __shfl_down(ss, off);
    }
    __shared__ float red[8];
    const int wave = tid >> 6, lane = tid & 63;
    if (lane == 0) { red[wave] = s; red[4 + wave] = ss; }
    __syncthreads();
    const float S  = red[0] + red[1] + red[2] + red[3];
    const float SS = red[4] + red[5] + red[6] + red[7];
    const float mu  = S * (1.0f / D_);
    const float var = SS * (1.0f / D_) - mu * mu;
    const float rs  = rsqrtf(var + 1e-5f);
    const float4 g  = ((const float4*)gamma)[tid];
    const float4 bb = ((const float4*)beta)[tid];
    float o0 = (v.x - mu) * rs * g.x + bb.x;
    float o1 = (v.y - mu) * rs * g.y + bb.y;
    float o2 = (v.z - mu) * rs * g.z + bb.z;
    float o3 = (v.w - mu) * rs * g.w + bb.w;
    ushort h0, l0, h1, l1, h2, l2, h3, l3;
    split2(o0, h0, l0); split2(o1, h1, l1);
    split2(o2, h2, l2); split2(o3, h3, l3);
    *(ushort4*)(xn_h + (size_t)row * D_ + tid * 4) = make_ushort4(h0, h1, h2, h3);
    *(ushort4*)(xn_l + (size_t)row * D_ + tid * 4) = make_ushort4(l0, l1, l2, l3);
}

// ---------------------------------------------------------------------------
// Weight transpose+split: W [K][N] fp32 -> Th/Tl [N][K] bf16.
// 64x64 tile per block, LDS transpose, coalesced both sides.
// ---------------------------------------------------------------------------
__global__ __launch_bounds__(256) void wtrans_kernel(const float* __restrict__ W,
                                                     ushort* __restrict__ Th,
                                                     ushort* __restrict__ Tl,
                                                     int K, int N) {
    __shared__ float tile[64][68];
    const int tid = threadIdx.x;
    const int n0 = blockIdx.x * 64, k0 = blockIdx.y * 64;
    const int kr = tid >> 4, nc = (tid & 15) * 4;
    #pragma unroll
    for (int li = 0; li < 4; ++li) {
        const int k = kr + li * 16;
        *(float4*)&tile[k][nc] = *(const float4*)(W + (size_t)(k0 + k) * N + n0 + nc);
    }
    __syncthreads();
    const int nl = tid >> 2;            // local out-row 0..63
    const int ks = (tid & 3) * 16;      // k slot base
    ushort hbuf[16], lbuf[16];
    #pragma unroll
    for (int i = 0; i < 16; ++i) split2(tile[ks + i][nl], hbuf[i], lbuf[i]);
    ushort* th = Th + (size_t)(n0 + nl) * K + k0 + ks;
    ushort* tl = Tl + (size_t)(n0 + nl) * K + k0 + ks;
    #pragma unroll
    for (int i = 0; i < 4; ++i) {
        *(ushort4*)(th + i * 4) = make_ushort4(hbuf[i*4], hbuf[i*4+1], hbuf[i*4+2], hbuf[i*4+3]);
        *(ushort4*)(tl + i * 4) = make_ushort4(lbuf[i*4], lbuf[i*4+1], lbuf[i*4+2], lbuf[i*4+3]);
    }
}

// ---------------------------------------------------------------------------
// Split-bf16 MFMA GEMM: C[M,N] = (Ah+Al)[M,K] @ (Bh+Bl)^T[N,K]  (+ bias)
// 3-term: Ah*Bh + Ah*Bl + Al*Bh.  BM=BN=128, BK=64, 4 waves (2x2),
// mfma_f32_16x16x32_bf16, XOR-swizzled LDS (conflict-free frag reads).
// ---------------------------------------------------------------------------
__global__ __launch_bounds__(256) void gemm_split_kernel(
        const ushort* __restrict__ Ah, const ushort* __restrict__ Al,
        const ushort* __restrict__ Bh, const ushort* __restrict__ Bl,
        float* __restrict__ C, int M, int N, int K,
        const float* __restrict__ bias) {
    __shared__ __align__(16) ushort As_h[128 * 64], As_l[128 * 64];
    __shared__ __align__(16) ushort Bs_h[128 * 64], Bs_l[128 * 64];
    const int tid  = threadIdx.x;
    const int lane = tid & 63;
    const int wv   = tid >> 6;
    const int lr = lane & 15, lg = lane >> 4;
    const int wr = wv >> 1, wc = wv & 1;
    const int m0 = blockIdx.y * 128, n0 = blockIdx.x * 128;

    f32x4 acc[4][4];
    #pragma unroll
    for (int i = 0; i < 4; ++i)
        #pragma unroll
        for (int j = 0; j < 4; ++j) acc[i][j] = (f32x4){0.f, 0.f, 0.f, 0.f};

    const int sr = tid >> 3;         // staging row base 0..31
    const int ss = (tid & 7) * 16;   // staging byte slot in 128B row

    for (int k0 = 0; k0 < K; k0 += 64) {
        __syncthreads();
        #pragma unroll
        for (int li = 0; li < 4; ++li) {
            const int r = sr + li * 32;
            const size_t ga = (size_t)(m0 + r) * K + k0 + (ss >> 1);
            const size_t gb = (size_t)(n0 + r) * K + k0 + (ss >> 1);
            const int off = swz(r, ss);
            *(uint4*)((char*)As_h + off) = *(const uint4*)(Ah + ga);
            *(uint4*)((char*)As_l + off) = *(const uint4*)(Al + ga);
            *(uint4*)((char*)Bs_h + off) = *(const uint4*)(Bh + gb);
            *(uint4*)((char*)Bs_l + off) = *(const uint4*)(Bl + gb);
        }
        __syncthreads();
        #pragma unroll
        for (int kc = 0; kc < 2; ++kc) {
            const int cb = kc * 64 + lg * 16;
            short8 ah[4], al[4], bhf[4], blf[4];
            #pragma unroll
            for (int i = 0; i < 4; ++i) {
                const int ra = wr * 64 + i * 16 + lr;
                const int rb = wc * 64 + i * 16 + lr;
                ah[i]  = *(short8*)((char*)As_h + swz(ra, cb));
                al[i]  = *(short8*)((char*)As_l + swz(ra, cb));
                bhf[i] = *(short8*)((char*)Bs_h + swz(rb, cb));
                blf[i] = *(short8*)((char*)Bs_l + swz(rb, cb));
            }
            #pragma unroll
            for (int mi = 0; mi < 4; ++mi)
                #pragma unroll
                for (int ni = 0; ni < 4; ++ni) {
                    acc[mi][ni] = __builtin_amdgcn_mfma_f32_16x16x32_bf16(ah[mi], bhf[ni], acc[mi][ni], 0, 0, 0);
                    acc[mi][ni] = __builtin_amdgcn_mfma_f32_16x16x32_bf16(ah[mi], blf[ni], acc[mi][ni], 0, 0, 0);
                    acc[mi][ni] = __builtin_amdgcn_mfma_f32_16x16x32_bf16(al[mi], bhf[ni], acc[mi][ni], 0, 0, 0);
                }
        }
    }

    // Epilogue: C row = (lg*4+rr), col = lr within each 16x16 tile.
    #pragma unroll
    for (int mi = 0; mi < 4; ++mi) {
        #pragma unroll
        for (int rr = 0; rr < 4; ++rr) {
            const int row = m0 + wr * 64 + mi * 16 + lg * 4 + rr;
            float* crow = C + (size_t)row * N + n0 + wc * 64;
            #pragma unroll
            for (int ni = 0; ni < 4; ++ni) {
                const int col = ni * 16 + lr;
                float v = acc[mi][ni][rr];
                if (bias) v += bias[n0 + wc * 64 + col];
                crow[col] = v;
            }
        }
    }
}

// ---------------------------------------------------------------------------
// RoPE cos/sin table: [S_][32] each.
// ---------------------------------------------------------------------------
__global__ __launch_bounds__(256) void rope_table_kernel(float* __restrict__ cost,
                                                         float* __restrict__ sint) {
    const int idx = blockIdx.x * 256 + threadIdx.x;
    const int s = idx >> 5;
    const int i = idx & 31;
    const float inv = powf(10000.0f, -(2.0f * (float)i) / 64.0f);
    const float f = (float)s * inv;
    float sv, cv;
    sincosf(f, &sv, &cv);
    cost[idx] = cv;
    sint[idx] = sv;
}

// ---------------------------------------------------------------------------
// RoPE apply, in-place on q and k halves of the qkv buffer.
// ---------------------------------------------------------------------------
__global__ __launch_bounds__(256) void rope_apply_kernel(float* __restrict__ qkv,
                                                         const float* __restrict__ cost,
                                                         const float* __restrict__ sint) {
    const int idx = blockIdx.x * 256 + threadIdx.x;
    const int d = idx & 31;
    const int h = (idx >> 5) & 15;
    const int row = idx >> 9;
    const int spos = row & (S_ - 1);
    const size_t base = (size_t)row * N3_ + h * 64 + d;
    const float c  = cost[spos * 32 + d];
    const float sn = sint[spos * 32 + d];
    const float q1 = qkv[base], q2 = qkv[base + 32];
    qkv[base]      = q1 * c - q2 * sn;
    qkv[base + 32] = q1 * sn + q2 * c;
    const float k1 = qkv[base + 1024], k2 = qkv[base + 1056];
    qkv[base + 1024] = k1 * c - k2 * sn;
    qkv[base + 1056] = k1 * sn + k2 * c;
}

// ---------------------------------------------------------------------------
// Flash attention v4: split-bf16 MFMA (16x16x32).  Unchanged from round 4
// except the epilogue now emits pre-split bf16 hi/lo for the out-proj GEMM.
// ---------------------------------------------------------------------------
__global__ __launch_bounds__(256) void attn_mfma_kernel(const float* __restrict__ qkv,
                                                        ushort* __restrict__ att_h,
                                                        ushort* __restrict__ att_l) {
    __shared__ __align__(16) ushort Kh[64 * 64], Kl[64 * 64];
    __shared__ __align__(16) ushort Vh[64 * 64], Vl[64 * 64];
    __shared__ __align__(16) ushort Ph[4][16 * 64], Pl[4][16 * 64];

    const int tid  = threadIdx.x;
    const int lane = tid & 63;
    const int wv   = tid >> 6;
    const int lr   = lane & 15;
    const int lg   = lane >> 4;

    const int bh = blockIdx.x;
    const int b  = bh >> 4;
    const int h  = bh & 15;
    const int q0 = blockIdx.y * 64;

    const int qrow = q0 + wv * 16 + lr;
    const float* qp = qkv + ((size_t)(b * S_ + qrow)) * N3_ + h * 64;
    short8 qh[2], ql[2];
    #pragma unroll
    for (int kc = 0; kc < 2; ++kc) {
        float t8[8];
        *(float4*)(t8)     = *(const float4*)(qp + kc * 32 + lg * 8);
        *(float4*)(t8 + 4) = *(const float4*)(qp + kc * 32 + lg * 8 + 4);
        #pragma unroll
        for (int i = 0; i < 8; ++i) {
            ushort hi, lo;
            split2(t8[i] * 0.125f, hi, lo);
            qh[kc][i] = (short)hi;
            ql[kc][i] = (short)lo;
        }
    }

    f32x4 accO[4];
    #pragma unroll
    for (int t = 0; t < 4; ++t) accO[t] = (f32x4){0.f, 0.f, 0.f, 0.f};
    float mrun[4] = {-1e30f, -1e30f, -1e30f, -1e30f};
    float lrun[4] = {0.f, 0.f, 0.f, 0.f};

    const int kj = tid >> 2;
    const int kd = (tid & 3) * 16;
    const int vjp = tid >> 3;
    const int vdb = (tid & 7) * 8;

    for (int j0 = 0; j0 < S_; j0 += 64) {
        __syncthreads();

        {
            const float* krow = qkv + ((size_t)(b * S_ + j0 + kj)) * N3_ + 1024 + h * 64;
            #pragma unroll
            for (int f = 0; f < 4; ++f) {
                float t4[4];
                *(float4*)t4 = *(const float4*)(krow + kd + f * 4);
                ushort hb[4], lb[4];
                #pragma unroll
                for (int i = 0; i < 4; ++i) split2(t4[i], hb[i], lb[i]);
                const int off = swz(kj, (kd + f * 4) * 2);
                *(ushort4*)((char*)Kh + off) = make_ushort4(hb[0], hb[1], hb[2], hb[3]);
                *(ushort4*)((char*)Kl + off) = make_ushort4(lb[0], lb[1], lb[2], lb[3]);
            }
        }
        {
            const float* vrow0 = qkv + ((size_t)(b * S_ + j0 + 2 * vjp)) * N3_ + 2048 + h * 64 + vdb;
            const float* vrow1 = vrow0 + N3_;
            float r0[8], r1[8];
            *(float4*)(r0)     = *(const float4*)(vrow0);
            *(float4*)(r0 + 4) = *(const float4*)(vrow0 + 4);
            *(float4*)(r1)     = *(const float4*)(vrow1);
            *(float4*)(r1 + 4) = *(const float4*)(vrow1 + 4);
            #pragma unroll
            for (int i = 0; i < 8; ++i) {
                const int d = vdb + i;
                ushort h0, l0, h1, l1;
                split2(r0[i], h0, l0);
                split2(r1[i], h1, l1);
                const int off = swz(d, vjp * 4);
                *(uint*)((char*)Vh + off) = (uint)h0 | ((uint)h1 << 16);
                *(uint*)((char*)Vl + off) = (uint)l0 | ((uint)l1 << 16);
            }
        }
        __syncthreads();

        f32x4 accS[4];
        #pragma unroll
        for (int t = 0; t < 4; ++t) accS[t] = (f32x4){0.f, 0.f, 0.f, 0.f};
        #pragma unroll
        for (int kc = 0; kc < 2; ++kc) {
            #pragma unroll
            for (int t = 0; t < 4; ++t) {
                const int off = swz(t * 16 + lr, (kc * 32 + lg * 8) * 2);
                short8 bhf = *(short8*)((char*)Kh + off);
                short8 blf = *(short8*)((char*)Kl + off);
                accS[t] = __builtin_amdgcn_mfma_f32_16x16x32_bf16(qh[kc], bhf, accS[t], 0, 0, 0);
                accS[t] = __builtin_amdgcn_mfma_f32_16x16x32_bf16(qh[kc], blf, accS[t], 0, 0, 0);
                accS[t] = __builtin_amdgcn_mfma_f32_16x16x32_bf16(ql[kc], bhf, accS[t], 0, 0, 0);
            }
        }

        float p[4][4];
        float fac[4];
        #pragma unroll
        for (int r = 0; r < 4; ++r) {
            float v = fmaxf(fmaxf(accS[0][r], accS[1][r]), fmaxf(accS[2][r], accS[3][r]));
            v = fmaxf(v, __shfl_xor(v, 1));
            v = fmaxf(v, __shfl_xor(v, 2));
            v = fmaxf(v, __shfl_xor(v, 4));
            v = fmaxf(v, __shfl_xor(v, 8));
            const float mn = fmaxf(mrun[r], v);
            fac[r] = __expf(mrun[r] - mn);
            mrun[r] = mn;
            float rs = 0.f;
            #pragma unroll
            for (int t = 0; t < 4; ++t) {
                p[t][r] = __expf(accS[t][r] - mn);
                rs += p[t][r];
            }
            rs += __shfl_xor(rs, 1);
            rs += __shfl_xor(rs, 2);
            rs += __shfl_xor(rs, 4);
            rs += __shfl_xor(rs, 8);
            lrun[r] = lrun[r] * fac[r] + rs;
        }
        #pragma unroll
        for (int t = 0; t < 4; ++t)
            #pragma unroll
            for (int r = 0; r < 4; ++r) accO[t][r] *= fac[r];

        #pragma unroll
        for (int t = 0; t < 4; ++t)
            #pragma unroll
            for (int r = 0; r < 4; ++r) {
                ushort hi, lo;
                split2(p[t][r], hi, lo);
                const int off = swz(lg * 4 + r, (t * 16 + lr) * 2);
                *(ushort*)((char*)Ph[wv] + off) = hi;
                *(ushort*)((char*)Pl[wv] + off) = lo;
            }

        #pragma unroll
        for (int jc = 0; jc < 2; ++jc) {
            const int aoff = swz(lr, (jc * 32 + lg * 8) * 2);
            short8 pah = *(short8*)((char*)Ph[wv] + aoff);
            short8 pal = *(short8*)((char*)Pl[wv] + aoff);
            #pragma unroll
            for (int dt = 0; dt < 4; ++dt) {
                const int boff = swz(dt * 16 + lr, (jc * 32 + lg * 8) * 2);
                short8 vhf = *(short8*)((char*)Vh + boff);
                short8 vlf = *(short8*)((char*)Vl + boff);
                accO[dt] = __builtin_amdgcn_mfma_f32_16x16x32_bf16(pah, vhf, accO[dt], 0, 0, 0);
                accO[dt] = __builtin_amdgcn_mfma_f32_16x16x32_bf16(pah, vlf, accO[dt], 0, 0, 0);
                accO[dt] = __builtin_amdgcn_mfma_f32_16x16x32_bf16(pal, vhf, accO[dt], 0, 0, 0);
            }
        }
    }

    // ---- normalize, split, write hi/lo
    #pragma unroll
    for (int r = 0; r < 4; ++r) {
        const float inv_l = 1.0f / lrun[r];
        const int q = q0 + wv * 16 + lg * 4 + r;
        const size_t ob = ((size_t)(b * S_ + q)) * INNER_ + h * 64;
        #pragma unroll
        for (int dt = 0; dt < 4; ++dt) {
            ushort hi, lo;
            split2(accO[dt][r] * inv_l, hi, lo);
            att_h[ob + dt * 16 + lr] = hi;
            att_l[ob + dt * 16 + lr] = lo;
        }
    }
}

// ---------------------------------------------------------------------------
// Launch
// ---------------------------------------------------------------------------
extern "C" void kernel_launch(void* const* d_in, const int* in_sizes, int n_in,
                              void* d_out, int out_size, void* d_ws, size_t ws_size,
                              hipStream_t stream) {
    const float* x        = (const float*)d_in[0];
    const float* w_qkv    = (const float*)d_in[1];
    const float* w_out    = (const float*)d_in[2];
    const float* b_out    = (const float*)d_in[3];
    const float* ln_gamma = (const float*)d_in[4];
    const float* ln_beta  = (const float*)d_in[5];
    float* out = (float*)d_out;

    char* wsb = (char*)d_ws;
    // [0, 96M): qkv fp32
    float*  qkv   = (float*)wsb;
    // [96M, 128M): xn hi/lo (live until QKV gemm) overlaid by att hi/lo (live after attn)
    ushort* xn_h  = (ushort*)(wsb + 100663296);
    ushort* xn_l  = (ushort*)(wsb + 100663296 + 16777216);
    ushort* att_h = xn_h;
    ushort* att_l = xn_l;
    // [128M, 140M): w_qkv^T hi/lo (live until QKV gemm) overlaid by w_out^T hi/lo
    ushort* wqT_h = (ushort*)(wsb + 134217728);
    ushort* wqT_l = (ushort*)(wsb + 134217728 + 6291456);
    ushort* woT_h = wqT_h;
    ushort* woT_l = (ushort*)(wsb + 134217728 + 2097152);
    // [140M, 140.5M): rope tables
    float*  cost  = (float*)(wsb + 146800640);
    float*  sint  = cost + S_ * 32;

    // 1. LayerNorm -> split bf16
    ln_kernel<<<ROWS_, 256, 0, stream>>>(x, ln_gamma, ln_beta, xn_h, xn_l);

    // 2. w_qkv transpose+split: [1024][3072] -> [3072][1024] hi/lo
    wtrans_kernel<<<dim3(N3_ / 64, D_ / 64), 256, 0, stream>>>(w_qkv, wqT_h, wqT_l, D_, N3_);

    // 3. QKV projection (MFMA): [8192,1024] @ [1024,3072] -> fp32 qkv
    gemm_split_kernel<<<dim3(N3_ / 128, ROWS_ / 128), 256, 0, stream>>>(
        xn_h, xn_l, wqT_h, wqT_l, qkv, ROWS_, N3_, D_, nullptr);

    // 4. RoPE table + apply (fp32)
    rope_table_kernel<<<(S_ * 32) / 256, 256, 0, stream>>>(cost, sint);
    rope_apply_kernel<<<(B_ * S_ * H_ * 32) / 256, 256, 0, stream>>>(qkv, cost, sint);

    // 5. Attention (split-bf16 MFMA) -> split bf16 att
    attn_mfma_kernel<<<dim3(B_ * H_, S_ / 64), 256, 0, stream>>>(qkv, att_h, att_l);

    // 6. w_out transpose+split (after QKV gemm: overlays wqT region)
    wtrans_kernel<<<dim3(D_ / 64, D_ / 64), 256, 0, stream>>>(w_out, woT_h, woT_l, D_, D_);

    // 7. Output projection (MFMA) + bias -> d_out
    gemm_split_kernel<<<dim3(D_ / 128, ROWS_ / 128), 256, 0, stream>>>(
        att_h, att_l, woT_h, woT_l, out, ROWS_, D_, INNER_, b_out);
}